// Round 2
// baseline (392.862 us; speedup 1.0000x reference)
//
#include <hip/hip_runtime.h>
#include <hip/hip_bf16.h>
#include <stdint.h>

typedef unsigned short u16;
typedef __attribute__((ext_vector_type(8))) short short8;
typedef __attribute__((ext_vector_type(4))) float float4v;

// RNE float->bf16
__device__ __forceinline__ u16 f2bf(float x) {
    union { float f; unsigned int u; } v; v.f = x;
    unsigned int r = v.u + 0x7fffu + ((v.u >> 16) & 1u);
    return (u16)(r >> 16);
}

__device__ __forceinline__ void ld_g2l16(const void* g, void* l) {
    __builtin_amdgcn_global_load_lds(
        (const __attribute__((address_space(1))) void*)g,
        (__attribute__((address_space(3))) void*)l, 16, 0, 0);
}

// ---------------- Pass 1: tables -> bf16 (16 floats/thread) + pack W1 ------------
// W1pack[kc][t][lane][j] = W1[kc*32 + (lane>>4)*8 + j][t*16 + (lane&15)]
__global__ __launch_bounds__(256) void conv_pack(
    const float* __restrict__ zs, const float* __restrict__ zt,
    const float* __restrict__ W1,
    u16* __restrict__ zs_b, u16* __restrict__ zt_b, u16* __restrict__ w1p,
    int n16s, int n16t)
{
    int id = blockIdx.x * 256 + threadIdx.x;
    if (id < n16s + n16t) {
        const float* src; u16* dst; int i;
        if (id < n16s) { src = zs; dst = zs_b; i = id; }
        else           { src = zt; dst = zt_b; i = id - n16s; }
        const float4* p = (const float4*)src + (size_t)i * 4;
        float4 a = p[0], b = p[1], c = p[2], d = p[3];
        short8 o0, o1;
        o0[0] = (short)f2bf(a.x); o0[1] = (short)f2bf(a.y);
        o0[2] = (short)f2bf(a.z); o0[3] = (short)f2bf(a.w);
        o0[4] = (short)f2bf(b.x); o0[5] = (short)f2bf(b.y);
        o0[6] = (short)f2bf(b.z); o0[7] = (short)f2bf(b.w);
        o1[0] = (short)f2bf(c.x); o1[1] = (short)f2bf(c.y);
        o1[2] = (short)f2bf(c.z); o1[3] = (short)f2bf(c.w);
        o1[4] = (short)f2bf(d.x); o1[5] = (short)f2bf(d.y);
        o1[6] = (short)f2bf(d.z); o1[7] = (short)f2bf(d.w);
        short8* q = (short8*)(dst + (size_t)i * 16);
        q[0] = o0; q[1] = o1;
    } else {
        int w = id - (n16s + n16t);
        if (w < 4096) {
            int lanep = w & 63, t = (w >> 6) & 7, kc = w >> 9;
            short8 o;
#pragma unroll
            for (int j = 0; j < 8; ++j) {
                int k = kc * 32 + (lanep >> 4) * 8 + j;
                int n = t * 16 + (lanep & 15);
                o[j] = (short)f2bf(W1[k * 128 + n]);
            }
            *(short8*)(w1p + (size_t)w * 8) = o;
        }
    }
}

// ---------------- Pass 2: barrier-free gathered MFMA GEMM ------------------------
// W1 (64KB bf16, B-frag layout) lives in LDS, staged once per block.
// Each wave independently owns tiles of 64 edges x full n=128:
//   acc[4 mtl][8 ntl] (128 VGPRs), A-frags gathered straight from global
//   (one 64B line per edge per kc: lanes m15=edge, quad=16B offset),
//   A double-buffered over kc, next tile's indices prefetched.
__global__ __launch_bounds__(256, 2) void edge_mlp(
    const u16* __restrict__ zs, const u16* __restrict__ zt,
    const u16* __restrict__ w1p,
    const int* __restrict__ row, const int* __restrict__ col,
    const float* __restrict__ b1, const float* __restrict__ W2,
    const float* __restrict__ b2, float* __restrict__ out,
    int E, int nwaves)
{
    __shared__ u16 Blds[32768];   // 64 KB: full W1 in B-frag layout

    const int tid  = threadIdx.x;
    const int wave = tid >> 6, lane = tid & 63;
    const int m15 = lane & 15, quad = lane >> 4;

    // stage B (linear copy of w1p)
#pragma unroll
    for (int it = 0; it < 16; ++it) {
        int off = (wave * 16 + it) * 1024;
        ld_g2l16((const char*)w1p + off + lane * 16, (char*)Blds + off);
    }

    // per-lane epilogue params: col = ntl*16 + m15
    float b1v[8], w2v[8];
#pragma unroll
    for (int ntl = 0; ntl < 8; ++ntl) {
        b1v[ntl] = b1[ntl * 16 + m15];
        w2v[ntl] = W2[ntl * 16 + m15];
    }
    const float b2v = b2[0];

    __builtin_amdgcn_s_waitcnt(0);
    __syncthreads();

    const int T = (E + 63) >> 6;
    const int wgid = blockIdx.x * 4 + wave;

    int ridx[4], cidx[4];
    if (wgid < T) {
#pragma unroll
        for (int mtl = 0; mtl < 4; ++mtl) {
            int e = wgid * 64 + mtl * 16 + m15;
            e = e < E ? e : E - 1;
            ridx[mtl] = row[e];
            cidx[mtl] = col[e];
        }
    }

    for (int t = wgid; t < T; t += nwaves) {
        // kc=0 A loads (z_start half, offset quad*16B)
        short8 A[2][4];
#pragma unroll
        for (int mtl = 0; mtl < 4; ++mtl)
            A[0][mtl] = *(const short8*)(zs + (size_t)(unsigned)ridx[mtl] * 128 + quad * 8);

        // prefetch next tile's indices (covered by this tile's MFMA)
        int nridx[4], ncidx[4];
        int tn = t + nwaves;
        if (tn < T) {
#pragma unroll
            for (int mtl = 0; mtl < 4; ++mtl) {
                int e = tn * 64 + mtl * 16 + m15;
                e = e < E ? e : E - 1;
                nridx[mtl] = row[e];
                ncidx[mtl] = col[e];
            }
        }

        float4v acc[4][8];
#pragma unroll
        for (int a = 0; a < 4; ++a)
#pragma unroll
            for (int b = 0; b < 8; ++b)
                acc[a][b] = (float4v){0.f, 0.f, 0.f, 0.f};

#pragma unroll
        for (int kc = 0; kc < 8; ++kc) {
            const int cur = kc & 1, nxt = cur ^ 1;
            if (kc < 7) {
                int k2 = kc + 1;
#pragma unroll
                for (int mtl = 0; mtl < 4; ++mtl) {
                    const u16* base = (k2 < 4)
                        ? zs + (size_t)(unsigned)ridx[mtl] * 128 + k2 * 32
                        : zt + (size_t)(unsigned)cidx[mtl] * 128 + (k2 - 4) * 32;
                    A[nxt][mtl] = *(const short8*)(base + quad * 8);
                }
            }
#pragma unroll
            for (int g = 0; g < 2; ++g) {
                short8 Bf[4];
#pragma unroll
                for (int j = 0; j < 4; ++j)
                    Bf[j] = *(const short8*)(Blds + (size_t)((kc * 8 + g * 4 + j) * 64 + lane) * 8);
#pragma unroll
                for (int mtl = 0; mtl < 4; ++mtl)
#pragma unroll
                    for (int j = 0; j < 4; ++j)
                        acc[mtl][g * 4 + j] = __builtin_amdgcn_mfma_f32_16x16x32_bf16(
                            A[cur][mtl], Bf[j], acc[mtl][g * 4 + j], 0, 0, 0);
            }
        }

        // epilogue: +b1, relu, dot W2 (8 in-lane + 16-lane butterfly), store
#pragma unroll
        for (int mtl = 0; mtl < 4; ++mtl) {
            float4v part;
#pragma unroll
            for (int r = 0; r < 4; ++r) {
                float s = 0.f;
#pragma unroll
                for (int ntl = 0; ntl < 8; ++ntl) {
                    float h = acc[mtl][ntl][r] + b1v[ntl];
                    h = h > 0.f ? h : 0.f;
                    s = fmaf(h, w2v[ntl], s);
                }
                s += __shfl_xor(s, 1);
                s += __shfl_xor(s, 2);
                s += __shfl_xor(s, 4);
                s += __shfl_xor(s, 8);
                part[r] = s + b2v;
            }
            if (m15 == 0) {
                int e0 = t * 64 + mtl * 16 + quad * 4;
                if (e0 + 3 < E) {
                    *(float4v*)(out + e0) = part;
                } else {
#pragma unroll
                    for (int r = 0; r < 4; ++r)
                        if (e0 + r < E) out[e0 + r] = part[r];
                }
            }
        }

#pragma unroll
        for (int mtl = 0; mtl < 4; ++mtl) {
            ridx[mtl] = nridx[mtl];
            cidx[mtl] = ncidx[mtl];
        }
    }
}

// ---------------- Fallback (fp32, slow but correct) if workspace too small -------
__global__ __launch_bounds__(256) void edge_mlp_naive(
    const float* __restrict__ zs, const float* __restrict__ zt,
    const int* __restrict__ row, const int* __restrict__ col,
    const float* __restrict__ W1, const float* __restrict__ b1,
    const float* __restrict__ W2, const float* __restrict__ b2,
    float* __restrict__ out, int E)
{
    __shared__ float zr[4][256];
    int wave = threadIdx.x >> 6, lane = threadIdx.x & 63;
    int e = blockIdx.x * 4 + wave;
    int ec = e < E ? e : E - 1;
    const float* a = zs + (size_t)row[ec] * 128;
    const float* bb = zt + (size_t)col[ec] * 128;
    zr[wave][lane] = a[lane];
    zr[wave][64 + lane] = a[64 + lane];
    zr[wave][128 + lane] = bb[lane];
    zr[wave][192 + lane] = bb[64 + lane];
    __syncthreads();
    float h0 = b1[lane], h1 = b1[64 + lane];
    for (int k = 0; k < 256; ++k) {
        float zk = zr[wave][k];
        h0 = fmaf(zk, W1[k * 128 + lane], h0);
        h1 = fmaf(zk, W1[k * 128 + 64 + lane], h1);
    }
    h0 = h0 > 0.f ? h0 : 0.f;
    h1 = h1 > 0.f ? h1 : 0.f;
    float s = fmaf(h0, W2[lane], h1 * W2[64 + lane]);
    for (int m = 1; m < 64; m <<= 1) s += __shfl_xor(s, m);
    if (lane == 0 && e < E) out[e] = s + b2[0];
}

extern "C" void kernel_launch(void* const* d_in, const int* in_sizes, int n_in,
                              void* d_out, int out_size, void* d_ws, size_t ws_size,
                              hipStream_t stream) {
    const float* zs = (const float*)d_in[0];
    const float* zt = (const float*)d_in[1];
    const int*  row = (const int*)d_in[2];
    const int*  col = (const int*)d_in[3];
    const float* W1 = (const float*)d_in[4];
    const float* b1 = (const float*)d_in[5];
    const float* W2 = (const float*)d_in[6];
    const float* b2 = (const float*)d_in[7];
    float* out = (float*)d_out;

    const int nzs = in_sizes[0];       // 12,800,000
    const int nzt = in_sizes[1];       // 6,400,000
    const int E   = in_sizes[2];       // 1,000,000

    const size_t need = ((size_t)nzs + (size_t)nzt + 32768) * 2;
    if (ws_size < need) {
        int nb = (E + 3) / 4;
        edge_mlp_naive<<<nb, 256, 0, stream>>>(zs, zt, row, col, W1, b1, W2, b2, out, E);
        return;
    }

    u16* zs_b = (u16*)d_ws;
    u16* zt_b = zs_b + nzs;
    u16* w1p  = zt_b + nzt;

    const int n16s = nzs / 16, n16t = nzt / 16;
    const int convN = n16s + n16t + 4096;
    conv_pack<<<(convN + 255) / 256, 256, 0, stream>>>(zs, zt, W1, zs_b, zt_b, w1p, n16s, n16t);

    // 512 blocks = 2/CU (64KB LDS each), 2048 waves grid-striding over edge tiles
    const int nblocks = 512;
    const int nwaves = nblocks * 4;
    edge_mlp<<<nblocks, 256, 0, stream>>>(zs_b, zt_b, w1p, row, col, b1, W2, b2, out, E, nwaves);
}